// Round 11
// baseline (267.103 us; speedup 1.0000x reference)
//
#include <hip/hip_runtime.h>
#include <math.h>

#define BQ   8
#define CIN  256
#define HH   64
#define WW   64
#define COUT 256
#define K2   9
#define PCH  27

#define PT     64            // pixels per block (one full row)
#define CCH    32            // channels per chunk
#define NCHUNK (CIN / CCH)   // 8
#define NSTEP  72            // total MFMA K-steps (of 32)
#define NSUB   24            // sub-chunks (3 taps = 3 K-steps each)
#define SUBROW 104           // sub-chunk row stride in shorts (96 + 8 pad)
#define PLANE  (HH * WW)     // 4096

#define NXT    (BQ * HH * 4)                 // 2048 xt blocks
#define NPW    ((NSTEP * COUT * 4) / 256)    // 288 packw blocks
#define NPG    ((NSTEP * 32 * 4) / 256)      // 36 packpg blocks
#define NPREP  (NXT + NPW + NPG)             // 2372

typedef __attribute__((ext_vector_type(8))) short short8;
typedef __attribute__((ext_vector_type(4))) float f32x4;
typedef __attribute__((ext_vector_type(2))) float f32x2;

// raw barrier: waits LDS writes, does NOT drain vmcnt (global prefetches
// stay in flight); leading+trailing compiler memory fences pin ordering.
#define PIPE_BARRIER() do {                                   \
    asm volatile("s_waitcnt lgkmcnt(0)" ::: "memory");        \
    __builtin_amdgcn_s_barrier();                             \
    asm volatile("" ::: "memory");                            \
} while (0)

static __device__ __forceinline__ unsigned short f2bf(float f) {
    unsigned u = __builtin_bit_cast(unsigned, f);
    u += 0x7fff + ((u >> 16) & 1);          // round-to-nearest-even
    return (unsigned short)(u >> 16);
}
static __device__ __forceinline__ f32x2 up2(unsigned u) {   // 2 bf16 -> 2 f32
    f32x2 r;
    r[0] = __builtin_bit_cast(float, u << 16);
    r[1] = __builtin_bit_cast(float, u & 0xffff0000u);
    return r;
}
static __device__ __forceinline__ unsigned cvtpk(float lo, float hi) {
    unsigned r;
    asm("v_cvt_pk_bf16_f32 %0, %1, %2" : "=v"(r) : "v"(lo), "v"(hi));
    return r;
}

// ---------------------------------------------------------------------------
// Merged prep kernel: [0,2048) xT transpose; [2048,2336) packw; [2336,2372) packpg.
// (R8/R10-proven, unchanged.)
// ---------------------------------------------------------------------------
__global__ __launch_bounds__(256) void k_prep(const float* __restrict__ x,
                                              unsigned short* __restrict__ xT,
                                              const float* __restrict__ w,
                                              unsigned short* __restrict__ wp,
                                              const float* __restrict__ pgw,
                                              unsigned short* __restrict__ wpg) {
    __shared__ float tile[64][65];
    int blk = blockIdx.x;

    if (blk < NXT) {
        int cc  = blk & 3;
        int y   = (blk >> 2) & 63;
        int b   = blk >> 8;
        int t   = threadIdx.x;
        int c0  = cc * 64;

        const float* xp = x + ((size_t)(b * CIN + c0) * HH + y) * WW;
#pragma unroll
        for (int r = 0; r < 16; ++r) {
            int cl = r * 4 + (t >> 6);
            int xx = t & 63;
            tile[cl][xx] = xp[(size_t)cl * PLANE + xx];
        }
        __syncthreads();
        unsigned short* op = xT + ((size_t)b * PLANE + (size_t)y * WW) * CIN + c0;
#pragma unroll
        for (int r = 0; r < 16; ++r) {
            int xx = r * 4 + (t >> 6);
            int cl = t & 63;
            op[(size_t)xx * CIN + cl] = f2bf(tile[cl][xx]);
        }
    } else if (blk < NXT + NPW) {
        int t = (blk - NXT) * 256 + threadIdx.x;    // (s*256 + o)*4 + q
        int q = t & 3;
        int o = (t >> 2) & 255;
        int s = t >> 10;
        short8 sv;
#pragma unroll
        for (int j = 0; j < 8; ++j) {
            int pos   = s * 32 + q * 8 + j;         // 0..2303
            int chunk = pos / (CCH * K2);
            int pl    = pos % (CCH * K2);
            int ktap  = pl >> 5;
            int c     = chunk * CCH + (pl & 31);
            sv[j] = (short)f2bf(w[(o * CIN + c) * K2 + ktap]);
        }
        *(short8*)(wp + (size_t)t * 8) = sv;
    } else {
        int t = (blk - NXT - NPW) * 256 + threadIdx.x;   // (s*32 + o)*4 + q
        int q = t & 3;
        int o = (t >> 2) & 31;
        int s = t >> 7;
        short8 sv;
#pragma unroll
        for (int j = 0; j < 8; ++j) {
            int pos   = s * 32 + q * 8 + j;
            int chunk = pos / (CCH * K2);
            int pl    = pos % (CCH * K2);
            int ktap  = pl >> 5;
            int c     = chunk * CCH + (pl & 31);
            sv[j] = (o < PCH) ? (short)f2bf(pgw[(size_t)(o * CIN + c) * K2 + ktap]) : (short)0;
        }
        *(short8*)(wpg + (size_t)t * 8) = sv;
    }
}

// ---------------------------------------------------------------------------
// Kernel 0d: standalone param-generator (R10-proven 2-row tiling, unchanged).
// ---------------------------------------------------------------------------
__global__ __launch_bounds__(512, 2) void k_params(const unsigned short* __restrict__ xT,
                                                   const unsigned short* __restrict__ wpg,
                                                   const float* __restrict__ pgb,
                                                   float* __restrict__ pv) {
    __shared__ alignas(16) unsigned short s_rows[2][4][66][40];   // 42,240 B

    int blk = blockIdx.x;
    int swz = (blk & 7) * 32 + (blk >> 3);   // XCD-chunked (256 % 8 == 0)
    int b   = swz >> 5;
    int h0  = (swz & 31) * 2;
    int t   = threadIdx.x;

    int wv  = t >> 6;
    int lm  = t & 15;
    int lq  = (t >> 4) & 3;
    int ipg = wv >> 2;                  // oc tile 0..1 (oc 0-15 / 16-31)
    int seg = wv & 3;                   // n-segment 0..3 (32 cols each)
    int ryb = seg >> 1;                 // output-row within pair
    int pxb = (seg & 1) * 32;           // px base within row

    const unsigned short* xTb = xT + (size_t)b * PLANE * CIN;

    if (t < 64) {
        int buf = t >> 5;
        int ry  = (t >> 3) & 3;
        int col = ((t >> 2) & 1) * 65;
        int q   = t & 3;
        uint4 z = make_uint4(0, 0, 0, 0);
        *(uint4*)&s_rows[buf][ry][col][q * 8] = z;
    }
    __syncthreads();

    f32x4 acc0 = (f32x4){0.f, 0.f, 0.f, 0.f};
    f32x4 acc1 = (f32x4){0.f, 0.f, 0.f, 0.f};

    int pxm1 = t >> 3;                  // 0..63 (staging pixel)
    int cgs  = (t & 7) * 4;             // short offset within 32-ch chunk

    uint2 R[4];
#pragma unroll
    for (int ry = 0; ry < 4; ++ry) {
        int y = h0 + ry - 1;
        R[ry] = make_uint2(0, 0);
        if ((unsigned)y < (unsigned)HH)
            R[ry] = *(const uint2*)(xTb + (size_t)(y * WW + pxm1) * CIN + cgs);
    }

    for (int ch = 0; ch < NCHUNK; ++ch) {
#pragma unroll
        for (int ry = 0; ry < 4; ++ry)
            *(uint2*)&s_rows[ch & 1][ry][pxm1 + 1][cgs] = R[ry];
        if (ch + 1 < NCHUNK) {
#pragma unroll
            for (int ry = 0; ry < 4; ++ry) {
                int y = h0 + ry - 1;
                R[ry] = make_uint2(0, 0);
                if ((unsigned)y < (unsigned)HH)
                    R[ry] = *(const uint2*)(xTb + (size_t)(y * WW + pxm1) * CIN
                                            + (ch + 1) * CCH + cgs);
            }
        }
        __syncthreads();
#pragma unroll
        for (int tap = 0; tap < K2; ++tap) {
            int ky = tap / 3, kx = tap % 3;
            short8 a  = *(const short8*)(wpg + (size_t)(ch * K2 + tap) * 32 * 32
                                         + (ipg * 16 + lm) * 32 + lq * 8);
            short8 bf0 = *(const short8*)&s_rows[ch & 1][ryb + ky][pxb +  0 + lm + kx][lq * 8];
            short8 bf1 = *(const short8*)&s_rows[ch & 1][ryb + ky][pxb + 16 + lm + kx][lq * 8];
            acc0 = __builtin_amdgcn_mfma_f32_16x16x32_bf16(a, bf0, acc0, 0, 0, 0);
            acc1 = __builtin_amdgcn_mfma_f32_16x16x32_bf16(a, bf1, acc1, 0, 0, 0);
        }
    }

    float* pvo = pv + ((size_t)(b * PCH) << 12) + (h0 + ryb) * WW;
#pragma unroll
    for (int rg = 0; rg < 4; ++rg) {
        int oc = ipg * 16 + lq * 4 + rg;
        if (oc < PCH) {
            float bb = pgb[oc];
            pvo[((size_t)oc << 12) + pxb +  0 + lm] = acc0[rg] + bb;
            pvo[((size_t)oc << 12) + pxb + 16 + lm] = acc1[rg] + bb;
        }
    }
}

// ---------------------------------------------------------------------------
// Fused kernel: tables -> deform-conv GEMM.
// Round 11: PRODUCER/CONSUMER wave specialization (sum-of-pipes -> max).
//   - waves 0-3 PRODUCERS: gather (uint4, 8 ch/thread) + combine + ds_write;
//     G[3][4] uint4 prefetch, distance 1 interval (R4-proven schedule).
//   - waves 4-7 CONSUMERS: each owns 64 outs x full 64 px: 4 A-frags
//     (prefetched 1 step ahead; wp read ONCE per block, no duplication)
//     + 4 B ds_reads + 16 MFMA per step. B ds_read volume halves.
//   - barrier/parity arithmetic BIT-IDENTICAL to R4/R10 (only thread-role
//     assignment changes); one PIPE_BARRIER per 3-tap interval.
//   - per SIMD (2 blocks/CU): 2 producer + 2 consumer waves -> MFMA pipe
//     and VALU/TA pipes overlap instead of convoying.
// ---------------------------------------------------------------------------
__global__ __launch_bounds__(512, 4) void k_fused(const unsigned short* __restrict__ xT,
                                                  const unsigned short* __restrict__ wp,
                                                  const float* __restrict__ pv,
                                                  const float* __restrict__ bias,
                                                  float* __restrict__ out) {
    __shared__ alignas(16) unsigned short s_samp[2][PT][SUBROW]; // 26,624 B
    __shared__ float4 s_wgt4[K2][PT];                            //  9,216 B
    __shared__ int4   s_off4[K2][PT];                            //  9,216 B

    int blk = blockIdx.x;
    int swz = (blk & 7) * 64 + (blk >> 3);   // XCD-chunked (512 % 8 == 0)
    int b   = swz >> 6;
    int h   = swz & 63;
    int t   = threadIdx.x;

    int wv = t >> 6;                    // wave 0..7
    int lm = t & 15;
    int lq = (t >> 4) & 3;

    const char* xTb = (const char*)xT + (size_t)b * PLANE * CIN * 2;

    // ================= Phase B: sampling tables (all waves) =================
    const float* pvb = pv + ((size_t)(b * PCH) << 12) + h * WW;
    for (int e = t; e < K2 * PT; e += 512) {
        int k = e >> 6;
        int p = e & 63;
        float dy = pvb[(size_t)(2 * k) << 12 | (unsigned)p];
        float dx = pvb[(size_t)(2 * k + 1) << 12 | (unsigned)p];
        float mz = pvb[(size_t)(18 + k) << 12 | (unsigned)p];
        float m  = 1.f / (1.f + expf(-mz));

        float py = dy + (float)(h - 1 + k / 3);
        float px = dx + (float)(p - 1 + k % 3);
        float y0f = floorf(py), x0f = floorf(px);
        float fy = py - y0f,    fx = px - x0f;
        int iy0 = (int)y0f, ix0 = (int)x0f;
        int iy1 = iy0 + 1,  ix1 = ix0 + 1;
        bool vy0 = (unsigned)iy0 < (unsigned)HH;
        bool vy1 = (unsigned)iy1 < (unsigned)HH;
        bool vx0 = (unsigned)ix0 < (unsigned)WW;
        bool vx1 = (unsigned)ix1 < (unsigned)WW;

        float w00 = (1.f - fy) * (1.f - fx) * m; if (!(vy0 && vx0)) w00 = 0.f;
        float w01 = (1.f - fy) * fx         * m; if (!(vy0 && vx1)) w01 = 0.f;
        float w10 = fy         * (1.f - fx) * m; if (!(vy1 && vx0)) w10 = 0.f;
        float w11 = fy         * fx         * m; if (!(vy1 && vx1)) w11 = 0.f;

        int cy0 = min(max(iy0, 0), HH - 1), cy1 = min(max(iy1, 0), HH - 1);
        int cx0 = min(max(ix0, 0), WW - 1), cx1 = min(max(ix1, 0), WW - 1);

        s_wgt4[k][p] = make_float4(w00, w01, w10, w11);
        s_off4[k][p] = make_int4((cy0 * WW + cx0) * 512, (cy0 * WW + cx1) * 512,
                                 (cy1 * WW + cx0) * 512, (cy1 * WW + cx1) * 512);
    }
    __syncthreads();

    // ================= Phase C: producer/consumer pipeline =================
    bool producer = (wv < 4);
    // producer roles (threads 0..255)
    int gp = t >> 2;                    // gather pixel 0..63
    int cq = t & 3;                     // 8-channel quarter 0..3 (byte off cq*16)
    // consumer roles
    int ow = (wv - 4) * 64;             // 64 outputs per consumer wave

    f32x4 acc[4][4];
#pragma unroll
    for (int i = 0; i < 4; ++i)
#pragma unroll
        for (int j = 0; j < 4; ++j) acc[i][j] = (f32x4){0.f, 0.f, 0.f, 0.f};

    uint4 G[3][4];                      // producer: 48 VGPR gather prefetch
    short8 aC[4], aN[4];                // consumer: A fragments

    if (producer) {
        // prologue: gather+combine sub-chunk 0, issue sub-chunk-1 loads
#pragma unroll
        for (int j = 0; j < 3; ++j) {
            int4 ob = s_off4[j][gp];
            G[j][0] = *(const uint4*)(xTb + ob.x + cq * 16);
            G[j][1] = *(const uint4*)(xTb + ob.y + cq * 16);
            G[j][2] = *(const uint4*)(xTb + ob.z + cq * 16);
            G[j][3] = *(const uint4*)(xTb + ob.w + cq * 16);
        }
#pragma unroll
        for (int j = 0; j < 3; ++j) {
            float4 gw = s_wgt4[j][gp];
            f32x2 v01 = gw.x * up2(G[j][0].x) + gw.y * up2(G[j][1].x)
                      + gw.z * up2(G[j][2].x) + gw.w * up2(G[j][3].x);
            f32x2 v23 = gw.x * up2(G[j][0].y) + gw.y * up2(G[j][1].y)
                      + gw.z * up2(G[j][2].y) + gw.w * up2(G[j][3].y);
            f32x2 v45 = gw.x * up2(G[j][0].z) + gw.y * up2(G[j][1].z)
                      + gw.z * up2(G[j][2].z) + gw.w * up2(G[j][3].z);
            f32x2 v67 = gw.x * up2(G[j][0].w) + gw.y * up2(G[j][1].w)
                      + gw.z * up2(G[j][2].w) + gw.w * up2(G[j][3].w);
            uint4 pk;
            pk.x = cvtpk(v01[0], v01[1]);
            pk.y = cvtpk(v23[0], v23[1]);
            pk.z = cvtpk(v45[0], v45[1]);
            pk.w = cvtpk(v67[0], v67[1]);
            *(uint4*)&s_samp[0][gp][j * 32 + cq * 8] = pk;
        }
#pragma unroll
        for (int j = 0; j < 3; ++j) {
            int4 ob = s_off4[3 + j][gp];
            G[j][0] = *(const uint4*)(xTb + ob.x + cq * 16);
            G[j][1] = *(const uint4*)(xTb + ob.y + cq * 16);
            G[j][2] = *(const uint4*)(xTb + ob.z + cq * 16);
            G[j][3] = *(const uint4*)(xTb + ob.w + cq * 16);
        }
    } else {
        // consumer prologue: load K-step-0 A fragments (64 outs)
#pragma unroll
        for (int i = 0; i < 4; ++i)
            aC[i] = *(const short8*)(wp + (ow + i * 16 + lm) * 32 + lq * 8);
    }
    PIPE_BARRIER();

    for (int sc = 0; sc < NSUB; ++sc) {
        unsigned short (*__restrict__ bc)[SUBROW] = s_samp[sc & 1];
        unsigned short (*__restrict__ bn)[SUBROW] = s_samp[(sc + 1) & 1];
        if (producer) {
            bool doC = (sc + 1 < NSUB);
            bool doL = (sc + 2 < NSUB);
            int t1 = ((sc + 1) % 3) * 3;
            int t2 = ((sc + 2) % 3) * 3;
            int c2 = ((sc + 2) / 3) * (CCH * 2) + cq * 16;
#pragma unroll
            for (int sl = 0; sl < 3; ++sl) {
                if (doC) {              // combine sub-chunk sc+1, tap sl -> bn
                    float4 gw = s_wgt4[t1 + sl][gp];
                    f32x2 v01 = gw.x * up2(G[sl][0].x) + gw.y * up2(G[sl][1].x)
                              + gw.z * up2(G[sl][2].x) + gw.w * up2(G[sl][3].x);
                    f32x2 v23 = gw.x * up2(G[sl][0].y) + gw.y * up2(G[sl][1].y)
                              + gw.z * up2(G[sl][2].y) + gw.w * up2(G[sl][3].y);
                    f32x2 v45 = gw.x * up2(G[sl][0].z) + gw.y * up2(G[sl][1].z)
                              + gw.z * up2(G[sl][2].z) + gw.w * up2(G[sl][3].z);
                    f32x2 v67 = gw.x * up2(G[sl][0].w) + gw.y * up2(G[sl][1].w)
                              + gw.z * up2(G[sl][2].w) + gw.w * up2(G[sl][3].w);
                    uint4 pk;
                    pk.x = cvtpk(v01[0], v01[1]);
                    pk.y = cvtpk(v23[0], v23[1]);
                    pk.z = cvtpk(v45[0], v45[1]);
                    pk.w = cvtpk(v67[0], v67[1]);
                    *(uint4*)&bn[gp][sl * 32 + cq * 8] = pk;
                }
                if (doL) {              // prefetch sub-chunk sc+2, tap sl
                    int4 ob = s_off4[t2 + sl][gp];
                    G[sl][0] = *(const uint4*)(xTb + ob.x + c2);
                    G[sl][1] = *(const uint4*)(xTb + ob.y + c2);
                    G[sl][2] = *(const uint4*)(xTb + ob.z + c2);
                    G[sl][3] = *(const uint4*)(xTb + ob.w + c2);
                }
            }
        } else {
#pragma unroll
            for (int sl = 0; sl < 3; ++sl) {
                short8 b0 = *(const short8*)&bc[ 0 + lm][sl * 32 + lq * 8];
                short8 b1 = *(const short8*)&bc[16 + lm][sl * 32 + lq * 8];
                short8 b2 = *(const short8*)&bc[32 + lm][sl * 32 + lq * 8];
                short8 b3 = *(const short8*)&bc[48 + lm][sl * 32 + lq * 8];
                int r = sc * 3 + sl + 1;
#pragma unroll
                for (int i = 0; i < 4; ++i) aN[i] = aC[i];
                if (r < NSTEP) {
                    const unsigned short* wrn = wp + (size_t)r * COUT * 32;
#pragma unroll
                    for (int i = 0; i < 4; ++i)
                        aN[i] = *(const short8*)(wrn + (ow + i * 16 + lm) * 32 + lq * 8);
                }
                acc[0][0] = __builtin_amdgcn_mfma_f32_16x16x32_bf16(aC[0], b0, acc[0][0], 0, 0, 0);
                acc[0][1] = __builtin_amdgcn_mfma_f32_16x16x32_bf16(aC[0], b1, acc[0][1], 0, 0, 0);
                acc[0][2] = __builtin_amdgcn_mfma_f32_16x16x32_bf16(aC[0], b2, acc[0][2], 0, 0, 0);
                acc[0][3] = __builtin_amdgcn_mfma_f32_16x16x32_bf16(aC[0], b3, acc[0][3], 0, 0, 0);
                acc[1][0] = __builtin_amdgcn_mfma_f32_16x16x32_bf16(aC[1], b0, acc[1][0], 0, 0, 0);
                acc[1][1] = __builtin_amdgcn_mfma_f32_16x16x32_bf16(aC[1], b1, acc[1][1], 0, 0, 0);
                acc[1][2] = __builtin_amdgcn_mfma_f32_16x16x32_bf16(aC[1], b2, acc[1][2], 0, 0, 0);
                acc[1][3] = __builtin_amdgcn_mfma_f32_16x16x32_bf16(aC[1], b3, acc[1][3], 0, 0, 0);
                acc[2][0] = __builtin_amdgcn_mfma_f32_16x16x32_bf16(aC[2], b0, acc[2][0], 0, 0, 0);
                acc[2][1] = __builtin_amdgcn_mfma_f32_16x16x32_bf16(aC[2], b1, acc[2][1], 0, 0, 0);
                acc[2][2] = __builtin_amdgcn_mfma_f32_16x16x32_bf16(aC[2], b2, acc[2][2], 0, 0, 0);
                acc[2][3] = __builtin_amdgcn_mfma_f32_16x16x32_bf16(aC[2], b3, acc[2][3], 0, 0, 0);
                acc[3][0] = __builtin_amdgcn_mfma_f32_16x16x32_bf16(aC[3], b0, acc[3][0], 0, 0, 0);
                acc[3][1] = __builtin_amdgcn_mfma_f32_16x16x32_bf16(aC[3], b1, acc[3][1], 0, 0, 0);
                acc[3][2] = __builtin_amdgcn_mfma_f32_16x16x32_bf16(aC[3], b2, acc[3][2], 0, 0, 0);
                acc[3][3] = __builtin_amdgcn_mfma_f32_16x16x32_bf16(aC[3], b3, acc[3][3], 0, 0, 0);
#pragma unroll
                for (int i = 0; i < 4; ++i) aC[i] = aN[i];
            }
        }
        PIPE_BARRIER();
    }

    // ================= epilogue (consumers only) =================
    if (!producer) {
        float* op = out + ((size_t)b * COUT) * PLANE + h * WW;
#pragma unroll
        for (int i = 0; i < 4; ++i) {
            int o0 = ow + i * 16 + lq * 4;
            f32x4 bv = *(const f32x4*)(bias + o0);
#pragma unroll
            for (int rg = 0; rg < 4; ++rg) {
#pragma unroll
                for (int j = 0; j < 4; ++j)
                    op[(size_t)(o0 + rg) * PLANE + j * 16 + lm] = acc[i][j][rg] + bv[rg];
            }
        }
    }
}

// ---------------------------------------------------------------------------
extern "C" void kernel_launch(void* const* d_in, const int* in_sizes, int n_in,
                              void* d_out, int out_size, void* d_ws, size_t ws_size,
                              hipStream_t stream) {
    const float* x    = (const float*)d_in[0];
    const float* wgt  = (const float*)d_in[1];
    const float* bias = (const float*)d_in[2];
    const float* pgw  = (const float*)d_in[3];
    const float* pgb  = (const float*)d_in[4];
    float* out = (float*)d_out;

    const size_t WPK_B = (size_t)NSTEP * COUT * 32 * 2;   //  1,179,648
    const size_t WPG_B = (size_t)NSTEP * 32 * 32 * 2;     //    147,456
    const size_t XT_B  = (size_t)BQ * PLANE * CIN * 2;    // 16,777,216
    unsigned short* wpk = (unsigned short*)d_ws;
    unsigned short* wpg = (unsigned short*)((char*)d_ws + WPK_B);
    unsigned short* xT  = (unsigned short*)((char*)d_ws + WPK_B + WPG_B);
    float*          pv  = (float*)((char*)d_ws + WPK_B + WPG_B + XT_B);  // 3.54 MB

    k_prep  <<<NPREP, 256, 0, stream>>>(x, xT, wgt, wpk, pgw, wpg);
    k_params<<<BQ * HH / 2, 512, 0, stream>>>(xT, wpg, pgb, pv);
    k_fused <<<BQ * HH, 512, 0, stream>>>(xT, wpk, pv, bias, out);
}

// Round 12
// 127.431 us; speedup vs baseline: 2.0961x; 2.0961x over previous
//
#include <hip/hip_runtime.h>
#include <math.h>

#define BQ   8
#define CIN  256
#define HH   64
#define WW   64
#define COUT 256
#define K2   9
#define PCH  27

#define PT     64            // pixels per block (one full row)
#define CCH    32            // channels per chunk
#define NCHUNK (CIN / CCH)   // 8
#define NSTEP  72            // total MFMA K-steps (of 32)
#define NSUB   24            // sub-chunks (3 taps = 3 K-steps each)
#define SUBROW 104           // sub-chunk row stride in shorts (96 + 8 pad)
#define PLANE  (HH * WW)     // 4096

#define NXT    (BQ * HH * 4)                 // 2048 xt blocks
#define NPW    ((NSTEP * COUT * 4) / 256)    // 288 packw blocks
#define NPG    ((NSTEP * 32 * 4) / 256)      // 36 packpg blocks
#define NPREP  (NXT + NPW + NPG)             // 2372

typedef __attribute__((ext_vector_type(8))) short short8;
typedef __attribute__((ext_vector_type(4))) float f32x4;
typedef __attribute__((ext_vector_type(2))) float f32x2;

// raw barrier: waits LDS writes, does NOT drain vmcnt (global prefetches
// stay in flight); leading+trailing compiler memory fences pin ordering.
#define PIPE_BARRIER() do {                                   \
    asm volatile("s_waitcnt lgkmcnt(0)" ::: "memory");        \
    __builtin_amdgcn_s_barrier();                             \
    asm volatile("" ::: "memory");                            \
} while (0)

static __device__ __forceinline__ unsigned short f2bf(float f) {
    unsigned u = __builtin_bit_cast(unsigned, f);
    u += 0x7fff + ((u >> 16) & 1);          // round-to-nearest-even
    return (unsigned short)(u >> 16);
}
static __device__ __forceinline__ f32x2 up2(unsigned u) {   // 2 bf16 -> 2 f32
    f32x2 r;
    r[0] = __builtin_bit_cast(float, u << 16);
    r[1] = __builtin_bit_cast(float, u & 0xffff0000u);
    return r;
}
static __device__ __forceinline__ unsigned cvtpk(float lo, float hi) {
    unsigned r;
    asm("v_cvt_pk_bf16_f32 %0, %1, %2" : "=v"(r) : "v"(lo), "v"(hi));
    return r;
}

// ---------------------------------------------------------------------------
// Merged prep kernel: [0,2048) xT transpose; [2048,2336) packw; [2336,2372) packpg.
// (R8/R10-proven, unchanged.)
// ---------------------------------------------------------------------------
__global__ __launch_bounds__(256) void k_prep(const float* __restrict__ x,
                                              unsigned short* __restrict__ xT,
                                              const float* __restrict__ w,
                                              unsigned short* __restrict__ wp,
                                              const float* __restrict__ pgw,
                                              unsigned short* __restrict__ wpg) {
    __shared__ float tile[64][65];
    int blk = blockIdx.x;

    if (blk < NXT) {
        int cc  = blk & 3;
        int y   = (blk >> 2) & 63;
        int b   = blk >> 8;
        int t   = threadIdx.x;
        int c0  = cc * 64;

        const float* xp = x + ((size_t)(b * CIN + c0) * HH + y) * WW;
#pragma unroll
        for (int r = 0; r < 16; ++r) {
            int cl = r * 4 + (t >> 6);
            int xx = t & 63;
            tile[cl][xx] = xp[(size_t)cl * PLANE + xx];
        }
        __syncthreads();
        unsigned short* op = xT + ((size_t)b * PLANE + (size_t)y * WW) * CIN + c0;
#pragma unroll
        for (int r = 0; r < 16; ++r) {
            int xx = r * 4 + (t >> 6);
            int cl = t & 63;
            op[(size_t)xx * CIN + cl] = f2bf(tile[cl][xx]);
        }
    } else if (blk < NXT + NPW) {
        int t = (blk - NXT) * 256 + threadIdx.x;    // (s*256 + o)*4 + q
        int q = t & 3;
        int o = (t >> 2) & 255;
        int s = t >> 10;
        short8 sv;
#pragma unroll
        for (int j = 0; j < 8; ++j) {
            int pos   = s * 32 + q * 8 + j;         // 0..2303
            int chunk = pos / (CCH * K2);
            int pl    = pos % (CCH * K2);
            int ktap  = pl >> 5;
            int c     = chunk * CCH + (pl & 31);
            sv[j] = (short)f2bf(w[(o * CIN + c) * K2 + ktap]);
        }
        *(short8*)(wp + (size_t)t * 8) = sv;
    } else {
        int t = (blk - NXT - NPW) * 256 + threadIdx.x;   // (s*32 + o)*4 + q
        int q = t & 3;
        int o = (t >> 2) & 31;
        int s = t >> 7;
        short8 sv;
#pragma unroll
        for (int j = 0; j < 8; ++j) {
            int pos   = s * 32 + q * 8 + j;
            int chunk = pos / (CCH * K2);
            int pl    = pos % (CCH * K2);
            int ktap  = pl >> 5;
            int c     = chunk * CCH + (pl & 31);
            sv[j] = (o < PCH) ? (short)f2bf(pgw[(size_t)(o * CIN + c) * K2 + ktap]) : (short)0;
        }
        *(short8*)(wpg + (size_t)t * 8) = sv;
    }
}

// ---------------------------------------------------------------------------
// Kernel 0d: standalone param-generator (R10-proven 2-row tiling, unchanged).
// ---------------------------------------------------------------------------
__global__ __launch_bounds__(512, 2) void k_params(const unsigned short* __restrict__ xT,
                                                   const unsigned short* __restrict__ wpg,
                                                   const float* __restrict__ pgb,
                                                   float* __restrict__ pv) {
    __shared__ alignas(16) unsigned short s_rows[2][4][66][40];   // 42,240 B

    int blk = blockIdx.x;
    int swz = (blk & 7) * 32 + (blk >> 3);   // XCD-chunked (256 % 8 == 0)
    int b   = swz >> 5;
    int h0  = (swz & 31) * 2;
    int t   = threadIdx.x;

    int wv  = t >> 6;
    int lm  = t & 15;
    int lq  = (t >> 4) & 3;
    int ipg = wv >> 2;                  // oc tile 0..1 (oc 0-15 / 16-31)
    int seg = wv & 3;                   // n-segment 0..3 (32 cols each)
    int ryb = seg >> 1;                 // output-row within pair
    int pxb = (seg & 1) * 32;           // px base within row

    const unsigned short* xTb = xT + (size_t)b * PLANE * CIN;

    if (t < 64) {
        int buf = t >> 5;
        int ry  = (t >> 3) & 3;
        int col = ((t >> 2) & 1) * 65;
        int q   = t & 3;
        uint4 z = make_uint4(0, 0, 0, 0);
        *(uint4*)&s_rows[buf][ry][col][q * 8] = z;
    }
    __syncthreads();

    f32x4 acc0 = (f32x4){0.f, 0.f, 0.f, 0.f};
    f32x4 acc1 = (f32x4){0.f, 0.f, 0.f, 0.f};

    int pxm1 = t >> 3;                  // 0..63 (staging pixel)
    int cgs  = (t & 7) * 4;             // short offset within 32-ch chunk

    uint2 R[4];
#pragma unroll
    for (int ry = 0; ry < 4; ++ry) {
        int y = h0 + ry - 1;
        R[ry] = make_uint2(0, 0);
        if ((unsigned)y < (unsigned)HH)
            R[ry] = *(const uint2*)(xTb + (size_t)(y * WW + pxm1) * CIN + cgs);
    }

    for (int ch = 0; ch < NCHUNK; ++ch) {
#pragma unroll
        for (int ry = 0; ry < 4; ++ry)
            *(uint2*)&s_rows[ch & 1][ry][pxm1 + 1][cgs] = R[ry];
        if (ch + 1 < NCHUNK) {
#pragma unroll
            for (int ry = 0; ry < 4; ++ry) {
                int y = h0 + ry - 1;
                R[ry] = make_uint2(0, 0);
                if ((unsigned)y < (unsigned)HH)
                    R[ry] = *(const uint2*)(xTb + (size_t)(y * WW + pxm1) * CIN
                                            + (ch + 1) * CCH + cgs);
            }
        }
        __syncthreads();
#pragma unroll
        for (int tap = 0; tap < K2; ++tap) {
            int ky = tap / 3, kx = tap % 3;
            short8 a  = *(const short8*)(wpg + (size_t)(ch * K2 + tap) * 32 * 32
                                         + (ipg * 16 + lm) * 32 + lq * 8);
            short8 bf0 = *(const short8*)&s_rows[ch & 1][ryb + ky][pxb +  0 + lm + kx][lq * 8];
            short8 bf1 = *(const short8*)&s_rows[ch & 1][ryb + ky][pxb + 16 + lm + kx][lq * 8];
            acc0 = __builtin_amdgcn_mfma_f32_16x16x32_bf16(a, bf0, acc0, 0, 0, 0);
            acc1 = __builtin_amdgcn_mfma_f32_16x16x32_bf16(a, bf1, acc1, 0, 0, 0);
        }
    }

    float* pvo = pv + ((size_t)(b * PCH) << 12) + (h0 + ryb) * WW;
#pragma unroll
    for (int rg = 0; rg < 4; ++rg) {
        int oc = ipg * 16 + lq * 4 + rg;
        if (oc < PCH) {
            float bb = pgb[oc];
            pvo[((size_t)oc << 12) + pxb +  0 + lm] = acc0[rg] + bb;
            pvo[((size_t)oc << 12) + pxb + 16 + lm] = acc1[rg] + bb;
        }
    }
}

// ---------------------------------------------------------------------------
// Fused kernel: tables -> deform-conv GEMM.
// Round 12: R11's producer/consumer specialization (correctness-proven) with
// the register budget FIXED: __launch_bounds__(512, 2) -> 256 VGPR cap, no
// scratch spill (R11's 780 MB WRITE_SIZE was acc[4][4] spilling under the
// 128-VGPR cap of (512,4)). 1 block/CU, 2 waves/SIMD = 1 producer + 1
// consumer per SIMD (wave->SIMD round-robin puts waves {i,i+4} on SIMD i).
// ---------------------------------------------------------------------------
__global__ __launch_bounds__(512, 2) void k_fused(const unsigned short* __restrict__ xT,
                                                  const unsigned short* __restrict__ wp,
                                                  const float* __restrict__ pv,
                                                  const float* __restrict__ bias,
                                                  float* __restrict__ out) {
    __shared__ alignas(16) unsigned short s_samp[2][PT][SUBROW]; // 26,624 B
    __shared__ float4 s_wgt4[K2][PT];                            //  9,216 B
    __shared__ int4   s_off4[K2][PT];                            //  9,216 B

    int blk = blockIdx.x;
    int swz = (blk & 7) * 64 + (blk >> 3);   // XCD-chunked (512 % 8 == 0)
    int b   = swz >> 6;
    int h   = swz & 63;
    int t   = threadIdx.x;

    int wv = t >> 6;                    // wave 0..7
    int lm = t & 15;
    int lq = (t >> 4) & 3;

    const char* xTb = (const char*)xT + (size_t)b * PLANE * CIN * 2;

    // ================= Phase B: sampling tables (all waves) =================
    const float* pvb = pv + ((size_t)(b * PCH) << 12) + h * WW;
    for (int e = t; e < K2 * PT; e += 512) {
        int k = e >> 6;
        int p = e & 63;
        float dy = pvb[(size_t)(2 * k) << 12 | (unsigned)p];
        float dx = pvb[(size_t)(2 * k + 1) << 12 | (unsigned)p];
        float mz = pvb[(size_t)(18 + k) << 12 | (unsigned)p];
        float m  = 1.f / (1.f + expf(-mz));

        float py = dy + (float)(h - 1 + k / 3);
        float px = dx + (float)(p - 1 + k % 3);
        float y0f = floorf(py), x0f = floorf(px);
        float fy = py - y0f,    fx = px - x0f;
        int iy0 = (int)y0f, ix0 = (int)x0f;
        int iy1 = iy0 + 1,  ix1 = ix0 + 1;
        bool vy0 = (unsigned)iy0 < (unsigned)HH;
        bool vy1 = (unsigned)iy1 < (unsigned)HH;
        bool vx0 = (unsigned)ix0 < (unsigned)WW;
        bool vx1 = (unsigned)ix1 < (unsigned)WW;

        float w00 = (1.f - fy) * (1.f - fx) * m; if (!(vy0 && vx0)) w00 = 0.f;
        float w01 = (1.f - fy) * fx         * m; if (!(vy0 && vx1)) w01 = 0.f;
        float w10 = fy         * (1.f - fx) * m; if (!(vy1 && vx0)) w10 = 0.f;
        float w11 = fy         * fx         * m; if (!(vy1 && vx1)) w11 = 0.f;

        int cy0 = min(max(iy0, 0), HH - 1), cy1 = min(max(iy1, 0), HH - 1);
        int cx0 = min(max(ix0, 0), WW - 1), cx1 = min(max(ix1, 0), WW - 1);

        s_wgt4[k][p] = make_float4(w00, w01, w10, w11);
        s_off4[k][p] = make_int4((cy0 * WW + cx0) * 512, (cy0 * WW + cx1) * 512,
                                 (cy1 * WW + cx0) * 512, (cy1 * WW + cx1) * 512);
    }
    __syncthreads();

    // ================= Phase C: producer/consumer pipeline =================
    bool producer = (wv < 4);
    // producer roles (threads 0..255)
    int gp = t >> 2;                    // gather pixel 0..63
    int cq = t & 3;                     // 8-channel quarter 0..3 (byte off cq*16)
    // consumer roles
    int ow = (wv - 4) * 64;             // 64 outputs per consumer wave

    f32x4 acc[4][4];
#pragma unroll
    for (int i = 0; i < 4; ++i)
#pragma unroll
        for (int j = 0; j < 4; ++j) acc[i][j] = (f32x4){0.f, 0.f, 0.f, 0.f};

    uint4 G[3][4];                      // producer: 48 VGPR gather prefetch
    short8 aC[4], aN[4];                // consumer: A fragments

    if (producer) {
        // prologue: gather+combine sub-chunk 0, issue sub-chunk-1 loads
#pragma unroll
        for (int j = 0; j < 3; ++j) {
            int4 ob = s_off4[j][gp];
            G[j][0] = *(const uint4*)(xTb + ob.x + cq * 16);
            G[j][1] = *(const uint4*)(xTb + ob.y + cq * 16);
            G[j][2] = *(const uint4*)(xTb + ob.z + cq * 16);
            G[j][3] = *(const uint4*)(xTb + ob.w + cq * 16);
        }
#pragma unroll
        for (int j = 0; j < 3; ++j) {
            float4 gw = s_wgt4[j][gp];
            f32x2 v01 = gw.x * up2(G[j][0].x) + gw.y * up2(G[j][1].x)
                      + gw.z * up2(G[j][2].x) + gw.w * up2(G[j][3].x);
            f32x2 v23 = gw.x * up2(G[j][0].y) + gw.y * up2(G[j][1].y)
                      + gw.z * up2(G[j][2].y) + gw.w * up2(G[j][3].y);
            f32x2 v45 = gw.x * up2(G[j][0].z) + gw.y * up2(G[j][1].z)
                      + gw.z * up2(G[j][2].z) + gw.w * up2(G[j][3].z);
            f32x2 v67 = gw.x * up2(G[j][0].w) + gw.y * up2(G[j][1].w)
                      + gw.z * up2(G[j][2].w) + gw.w * up2(G[j][3].w);
            uint4 pk;
            pk.x = cvtpk(v01[0], v01[1]);
            pk.y = cvtpk(v23[0], v23[1]);
            pk.z = cvtpk(v45[0], v45[1]);
            pk.w = cvtpk(v67[0], v67[1]);
            *(uint4*)&s_samp[0][gp][j * 32 + cq * 8] = pk;
        }
#pragma unroll
        for (int j = 0; j < 3; ++j) {
            int4 ob = s_off4[3 + j][gp];
            G[j][0] = *(const uint4*)(xTb + ob.x + cq * 16);
            G[j][1] = *(const uint4*)(xTb + ob.y + cq * 16);
            G[j][2] = *(const uint4*)(xTb + ob.z + cq * 16);
            G[j][3] = *(const uint4*)(xTb + ob.w + cq * 16);
        }
    } else {
        // consumer prologue: load K-step-0 A fragments (64 outs)
#pragma unroll
        for (int i = 0; i < 4; ++i)
            aC[i] = *(const short8*)(wp + (ow + i * 16 + lm) * 32 + lq * 8);
    }
    PIPE_BARRIER();

    for (int sc = 0; sc < NSUB; ++sc) {
        unsigned short (*__restrict__ bc)[SUBROW] = s_samp[sc & 1];
        unsigned short (*__restrict__ bn)[SUBROW] = s_samp[(sc + 1) & 1];
        if (producer) {
            bool doC = (sc + 1 < NSUB);
            bool doL = (sc + 2 < NSUB);
            int t1 = ((sc + 1) % 3) * 3;
            int t2 = ((sc + 2) % 3) * 3;
            int c2 = ((sc + 2) / 3) * (CCH * 2) + cq * 16;
#pragma unroll
            for (int sl = 0; sl < 3; ++sl) {
                if (doC) {              // combine sub-chunk sc+1, tap sl -> bn
                    float4 gw = s_wgt4[t1 + sl][gp];
                    f32x2 v01 = gw.x * up2(G[sl][0].x) + gw.y * up2(G[sl][1].x)
                              + gw.z * up2(G[sl][2].x) + gw.w * up2(G[sl][3].x);
                    f32x2 v23 = gw.x * up2(G[sl][0].y) + gw.y * up2(G[sl][1].y)
                              + gw.z * up2(G[sl][2].y) + gw.w * up2(G[sl][3].y);
                    f32x2 v45 = gw.x * up2(G[sl][0].z) + gw.y * up2(G[sl][1].z)
                              + gw.z * up2(G[sl][2].z) + gw.w * up2(G[sl][3].z);
                    f32x2 v67 = gw.x * up2(G[sl][0].w) + gw.y * up2(G[sl][1].w)
                              + gw.z * up2(G[sl][2].w) + gw.w * up2(G[sl][3].w);
                    uint4 pk;
                    pk.x = cvtpk(v01[0], v01[1]);
                    pk.y = cvtpk(v23[0], v23[1]);
                    pk.z = cvtpk(v45[0], v45[1]);
                    pk.w = cvtpk(v67[0], v67[1]);
                    *(uint4*)&bn[gp][sl * 32 + cq * 8] = pk;
                }
                if (doL) {              // prefetch sub-chunk sc+2, tap sl
                    int4 ob = s_off4[t2 + sl][gp];
                    G[sl][0] = *(const uint4*)(xTb + ob.x + c2);
                    G[sl][1] = *(const uint4*)(xTb + ob.y + c2);
                    G[sl][2] = *(const uint4*)(xTb + ob.z + c2);
                    G[sl][3] = *(const uint4*)(xTb + ob.w + c2);
                }
            }
        } else {
#pragma unroll
            for (int sl = 0; sl < 3; ++sl) {
                short8 b0 = *(const short8*)&bc[ 0 + lm][sl * 32 + lq * 8];
                short8 b1 = *(const short8*)&bc[16 + lm][sl * 32 + lq * 8];
                short8 b2 = *(const short8*)&bc[32 + lm][sl * 32 + lq * 8];
                short8 b3 = *(const short8*)&bc[48 + lm][sl * 32 + lq * 8];
                int r = sc * 3 + sl + 1;
#pragma unroll
                for (int i = 0; i < 4; ++i) aN[i] = aC[i];
                if (r < NSTEP) {
                    const unsigned short* wrn = wp + (size_t)r * COUT * 32;
#pragma unroll
                    for (int i = 0; i < 4; ++i)
                        aN[i] = *(const short8*)(wrn + (ow + i * 16 + lm) * 32 + lq * 8);
                }
                acc[0][0] = __builtin_amdgcn_mfma_f32_16x16x32_bf16(aC[0], b0, acc[0][0], 0, 0, 0);
                acc[0][1] = __builtin_amdgcn_mfma_f32_16x16x32_bf16(aC[0], b1, acc[0][1], 0, 0, 0);
                acc[0][2] = __builtin_amdgcn_mfma_f32_16x16x32_bf16(aC[0], b2, acc[0][2], 0, 0, 0);
                acc[0][3] = __builtin_amdgcn_mfma_f32_16x16x32_bf16(aC[0], b3, acc[0][3], 0, 0, 0);
                acc[1][0] = __builtin_amdgcn_mfma_f32_16x16x32_bf16(aC[1], b0, acc[1][0], 0, 0, 0);
                acc[1][1] = __builtin_amdgcn_mfma_f32_16x16x32_bf16(aC[1], b1, acc[1][1], 0, 0, 0);
                acc[1][2] = __builtin_amdgcn_mfma_f32_16x16x32_bf16(aC[1], b2, acc[1][2], 0, 0, 0);
                acc[1][3] = __builtin_amdgcn_mfma_f32_16x16x32_bf16(aC[1], b3, acc[1][3], 0, 0, 0);
                acc[2][0] = __builtin_amdgcn_mfma_f32_16x16x32_bf16(aC[2], b0, acc[2][0], 0, 0, 0);
                acc[2][1] = __builtin_amdgcn_mfma_f32_16x16x32_bf16(aC[2], b1, acc[2][1], 0, 0, 0);
                acc[2][2] = __builtin_amdgcn_mfma_f32_16x16x32_bf16(aC[2], b2, acc[2][2], 0, 0, 0);
                acc[2][3] = __builtin_amdgcn_mfma_f32_16x16x32_bf16(aC[2], b3, acc[2][3], 0, 0, 0);
                acc[3][0] = __builtin_amdgcn_mfma_f32_16x16x32_bf16(aC[3], b0, acc[3][0], 0, 0, 0);
                acc[3][1] = __builtin_amdgcn_mfma_f32_16x16x32_bf16(aC[3], b1, acc[3][1], 0, 0, 0);
                acc[3][2] = __builtin_amdgcn_mfma_f32_16x16x32_bf16(aC[3], b2, acc[3][2], 0, 0, 0);
                acc[3][3] = __builtin_amdgcn_mfma_f32_16x16x32_bf16(aC[3], b3, acc[3][3], 0, 0, 0);
#pragma unroll
                for (int i = 0; i < 4; ++i) aC[i] = aN[i];
            }
        }
        PIPE_BARRIER();
    }

    // ================= epilogue (consumers only) =================
    if (!producer) {
        float* op = out + ((size_t)b * COUT) * PLANE + h * WW;
#pragma unroll
        for (int i = 0; i < 4; ++i) {
            int o0 = ow + i * 16 + lq * 4;
            f32x4 bv = *(const f32x4*)(bias + o0);
#pragma unroll
            for (int rg = 0; rg < 4; ++rg) {
#pragma unroll
                for (int j = 0; j < 4; ++j)
                    op[(size_t)(o0 + rg) * PLANE + j * 16 + lm] = acc[i][j][rg] + bv[rg];
            }
        }
    }
}

// ---------------------------------------------------------------------------
extern "C" void kernel_launch(void* const* d_in, const int* in_sizes, int n_in,
                              void* d_out, int out_size, void* d_ws, size_t ws_size,
                              hipStream_t stream) {
    const float* x    = (const float*)d_in[0];
    const float* wgt  = (const float*)d_in[1];
    const float* bias = (const float*)d_in[2];
    const float* pgw  = (const float*)d_in[3];
    const float* pgb  = (const float*)d_in[4];
    float* out = (float*)d_out;

    const size_t WPK_B = (size_t)NSTEP * COUT * 32 * 2;   //  1,179,648
    const size_t WPG_B = (size_t)NSTEP * 32 * 32 * 2;     //    147,456
    const size_t XT_B  = (size_t)BQ * PLANE * CIN * 2;    // 16,777,216
    unsigned short* wpk = (unsigned short*)d_ws;
    unsigned short* wpg = (unsigned short*)((char*)d_ws + WPK_B);
    unsigned short* xT  = (unsigned short*)((char*)d_ws + WPK_B + WPG_B);
    float*          pv  = (float*)((char*)d_ws + WPK_B + WPG_B + XT_B);  // 3.54 MB

    k_prep  <<<NPREP, 256, 0, stream>>>(x, xT, wgt, wpk, pgw, wpg);
    k_params<<<BQ * HH / 2, 512, 0, stream>>>(xT, wpg, pgb, pv);
    k_fused <<<BQ * HH, 512, 0, stream>>>(xT, wpk, pv, bias, out);
}

// Round 13
// 104.369 us; speedup vs baseline: 2.5592x; 1.2210x over previous
//
#include <hip/hip_runtime.h>
#include <math.h>

#define BQ   8
#define CIN  256
#define HH   64
#define WW   64
#define COUT 256
#define K2   9
#define PCH  27

#define PT     64            // pixels per block (one full row)
#define CCH    32            // channels per chunk
#define NCHUNK (CIN / CCH)   // 8
#define NSTEP  72            // total MFMA K-steps (of 32)
#define NSUB   24            // sub-chunks (3 taps = 3 K-steps each)
#define SUBROW 104           // sub-chunk row stride in shorts (96 + 8 pad)
#define PLANE  (HH * WW)     // 4096

#define NXT    (BQ * HH * 4)                 // 2048 xt blocks
#define NPW    ((NSTEP * COUT * 4) / 256)    // 288 packw blocks
#define NPG    ((NSTEP * 32 * 4) / 256)      // 36 packpg blocks
#define NPREP  (NXT + NPW + NPG)             // 2372

typedef __attribute__((ext_vector_type(8))) short short8;
typedef __attribute__((ext_vector_type(4))) float f32x4;
typedef __attribute__((ext_vector_type(2))) float f32x2;

// raw barrier: waits LDS writes, does NOT drain vmcnt (global prefetches
// stay in flight); leading+trailing compiler memory fences pin ordering.
#define PIPE_BARRIER() do {                                   \
    asm volatile("s_waitcnt lgkmcnt(0)" ::: "memory");        \
    __builtin_amdgcn_s_barrier();                             \
    asm volatile("" ::: "memory");                            \
} while (0)

static __device__ __forceinline__ unsigned short f2bf(float f) {
    unsigned u = __builtin_bit_cast(unsigned, f);
    u += 0x7fff + ((u >> 16) & 1);          // round-to-nearest-even
    return (unsigned short)(u >> 16);
}
static __device__ __forceinline__ f32x2 up2(unsigned u) {   // 2 bf16 -> 2 f32
    f32x2 r;
    r[0] = __builtin_bit_cast(float, u << 16);
    r[1] = __builtin_bit_cast(float, u & 0xffff0000u);
    return r;
}
static __device__ __forceinline__ unsigned cvtpk(float lo, float hi) {
    unsigned r;
    asm("v_cvt_pk_bf16_f32 %0, %1, %2" : "=v"(r) : "v"(lo), "v"(hi));
    return r;
}

// ---------------------------------------------------------------------------
// Merged prep kernel: [0,2048) xT transpose; [2048,2336) packw; [2336,2372) packpg.
// (R8/R10-proven, unchanged.)
// ---------------------------------------------------------------------------
__global__ __launch_bounds__(256) void k_prep(const float* __restrict__ x,
                                              unsigned short* __restrict__ xT,
                                              const float* __restrict__ w,
                                              unsigned short* __restrict__ wp,
                                              const float* __restrict__ pgw,
                                              unsigned short* __restrict__ wpg) {
    __shared__ float tile[64][65];
    int blk = blockIdx.x;

    if (blk < NXT) {
        int cc  = blk & 3;
        int y   = (blk >> 2) & 63;
        int b   = blk >> 8;
        int t   = threadIdx.x;
        int c0  = cc * 64;

        const float* xp = x + ((size_t)(b * CIN + c0) * HH + y) * WW;
#pragma unroll
        for (int r = 0; r < 16; ++r) {
            int cl = r * 4 + (t >> 6);
            int xx = t & 63;
            tile[cl][xx] = xp[(size_t)cl * PLANE + xx];
        }
        __syncthreads();
        unsigned short* op = xT + ((size_t)b * PLANE + (size_t)y * WW) * CIN + c0;
#pragma unroll
        for (int r = 0; r < 16; ++r) {
            int xx = r * 4 + (t >> 6);
            int cl = t & 63;
            op[(size_t)xx * CIN + cl] = f2bf(tile[cl][xx]);
        }
    } else if (blk < NXT + NPW) {
        int t = (blk - NXT) * 256 + threadIdx.x;    // (s*256 + o)*4 + q
        int q = t & 3;
        int o = (t >> 2) & 255;
        int s = t >> 10;
        short8 sv;
#pragma unroll
        for (int j = 0; j < 8; ++j) {
            int pos   = s * 32 + q * 8 + j;         // 0..2303
            int chunk = pos / (CCH * K2);
            int pl    = pos % (CCH * K2);
            int ktap  = pl >> 5;
            int c     = chunk * CCH + (pl & 31);
            sv[j] = (short)f2bf(w[(o * CIN + c) * K2 + ktap]);
        }
        *(short8*)(wp + (size_t)t * 8) = sv;
    } else {
        int t = (blk - NXT - NPW) * 256 + threadIdx.x;   // (s*32 + o)*4 + q
        int q = t & 3;
        int o = (t >> 2) & 31;
        int s = t >> 7;
        short8 sv;
#pragma unroll
        for (int j = 0; j < 8; ++j) {
            int pos   = s * 32 + q * 8 + j;
            int chunk = pos / (CCH * K2);
            int pl    = pos % (CCH * K2);
            int ktap  = pl >> 5;
            int c     = chunk * CCH + (pl & 31);
            sv[j] = (o < PCH) ? (short)f2bf(pgw[(size_t)(o * CIN + c) * K2 + ktap]) : (short)0;
        }
        *(short8*)(wpg + (size_t)t * 8) = sv;
    }
}

// ---------------------------------------------------------------------------
// Kernel 0d: standalone param-generator (R10-proven 2-row tiling, unchanged).
// Block computes output rows h0,h0+1 (M=32 oc x N=128 = 2x64 px) from 4
// staged input rows; dbuf + 1 sync per chunk; grid 256 = 1 block/CU.
// ---------------------------------------------------------------------------
__global__ __launch_bounds__(512, 2) void k_params(const unsigned short* __restrict__ xT,
                                                   const unsigned short* __restrict__ wpg,
                                                   const float* __restrict__ pgb,
                                                   float* __restrict__ pv) {
    __shared__ alignas(16) unsigned short s_rows[2][4][66][40];   // 42,240 B

    int blk = blockIdx.x;
    int swz = (blk & 7) * 32 + (blk >> 3);   // XCD-chunked (256 % 8 == 0)
    int b   = swz >> 5;
    int h0  = (swz & 31) * 2;
    int t   = threadIdx.x;

    int wv  = t >> 6;
    int lm  = t & 15;
    int lq  = (t >> 4) & 3;
    int ipg = wv >> 2;                  // oc tile 0..1 (oc 0-15 / 16-31)
    int seg = wv & 3;                   // n-segment 0..3 (32 cols each)
    int ryb = seg >> 1;                 // output-row within pair
    int pxb = (seg & 1) * 32;           // px base within row

    const unsigned short* xTb = xT + (size_t)b * PLANE * CIN;

    if (t < 64) {
        int buf = t >> 5;
        int ry  = (t >> 3) & 3;
        int col = ((t >> 2) & 1) * 65;
        int q   = t & 3;
        uint4 z = make_uint4(0, 0, 0, 0);
        *(uint4*)&s_rows[buf][ry][col][q * 8] = z;
    }
    __syncthreads();

    f32x4 acc0 = (f32x4){0.f, 0.f, 0.f, 0.f};
    f32x4 acc1 = (f32x4){0.f, 0.f, 0.f, 0.f};

    int pxm1 = t >> 3;                  // 0..63 (staging pixel)
    int cgs  = (t & 7) * 4;             // short offset within 32-ch chunk

    uint2 R[4];
#pragma unroll
    for (int ry = 0; ry < 4; ++ry) {
        int y = h0 + ry - 1;
        R[ry] = make_uint2(0, 0);
        if ((unsigned)y < (unsigned)HH)
            R[ry] = *(const uint2*)(xTb + (size_t)(y * WW + pxm1) * CIN + cgs);
    }

    for (int ch = 0; ch < NCHUNK; ++ch) {
#pragma unroll
        for (int ry = 0; ry < 4; ++ry)
            *(uint2*)&s_rows[ch & 1][ry][pxm1 + 1][cgs] = R[ry];
        if (ch + 1 < NCHUNK) {
#pragma unroll
            for (int ry = 0; ry < 4; ++ry) {
                int y = h0 + ry - 1;
                R[ry] = make_uint2(0, 0);
                if ((unsigned)y < (unsigned)HH)
                    R[ry] = *(const uint2*)(xTb + (size_t)(y * WW + pxm1) * CIN
                                            + (ch + 1) * CCH + cgs);
            }
        }
        __syncthreads();
#pragma unroll
        for (int tap = 0; tap < K2; ++tap) {
            int ky = tap / 3, kx = tap % 3;
            short8 a  = *(const short8*)(wpg + (size_t)(ch * K2 + tap) * 32 * 32
                                         + (ipg * 16 + lm) * 32 + lq * 8);
            short8 bf0 = *(const short8*)&s_rows[ch & 1][ryb + ky][pxb +  0 + lm + kx][lq * 8];
            short8 bf1 = *(const short8*)&s_rows[ch & 1][ryb + ky][pxb + 16 + lm + kx][lq * 8];
            acc0 = __builtin_amdgcn_mfma_f32_16x16x32_bf16(a, bf0, acc0, 0, 0, 0);
            acc1 = __builtin_amdgcn_mfma_f32_16x16x32_bf16(a, bf1, acc1, 0, 0, 0);
        }
    }

    float* pvo = pv + ((size_t)(b * PCH) << 12) + (h0 + ryb) * WW;
#pragma unroll
    for (int rg = 0; rg < 4; ++rg) {
        int oc = ipg * 16 + lq * 4 + rg;
        if (oc < PCH) {
            float bb = pgb[oc];
            pvo[((size_t)oc << 12) + pxb +  0 + lm] = acc0[rg] + bb;
            pvo[((size_t)oc << 12) + pxb + 16 + lm] = acc1[rg] + bb;
        }
    }
}

// ---------------------------------------------------------------------------
// Fused kernel: tables (from global params) -> deform-conv GEMM.
// R10-proven optimum (84.1 us): phase B + R4-pipelined phase C, no setprio.
// Session conclusion: this interleaved 2-block-convoy beats pipelining@1blk
// (R1), retiling (R5/R9), and wave specialization (R11/R12) -- all of which
// landed at 100-116 us. Structural plateau of this decomposition.
// ---------------------------------------------------------------------------
__global__ __launch_bounds__(512, 4) void k_fused(const unsigned short* __restrict__ xT,
                                                  const unsigned short* __restrict__ wp,
                                                  const float* __restrict__ pv,
                                                  const float* __restrict__ bias,
                                                  float* __restrict__ out) {
    __shared__ alignas(16) unsigned short s_samp[2][PT][SUBROW]; // 26,624 B
    __shared__ float4 s_wgt4[K2][PT];                            //  9,216 B
    __shared__ int4   s_off4[K2][PT];                            //  9,216 B

    int blk = blockIdx.x;
    int swz = (blk & 7) * 64 + (blk >> 3);   // XCD-chunked (512 % 8 == 0)
    int b   = swz >> 6;
    int h   = swz & 63;
    int t   = threadIdx.x;

    // roles
    int gp = t >> 3;                    // gather pixel 0..63
    int cg = t & 7;                     // 4-channel group 0..7
    int wv = t >> 6;                    // wave 0..7
    int lm = t & 15;
    int lq = (t >> 4) & 3;

    const char* xTb = (const char*)xT + (size_t)b * PLANE * CIN * 2;

    // ================= Phase B: sampling tables =================
    const float* pvb = pv + ((size_t)(b * PCH) << 12) + h * WW;
    for (int e = t; e < K2 * PT; e += 512) {
        int k = e >> 6;
        int p = e & 63;
        float dy = pvb[(size_t)(2 * k) << 12 | (unsigned)p];
        float dx = pvb[(size_t)(2 * k + 1) << 12 | (unsigned)p];
        float mz = pvb[(size_t)(18 + k) << 12 | (unsigned)p];
        float m  = 1.f / (1.f + expf(-mz));

        float py = dy + (float)(h - 1 + k / 3);
        float px = dx + (float)(p - 1 + k % 3);
        float y0f = floorf(py), x0f = floorf(px);
        float fy = py - y0f,    fx = px - x0f;
        int iy0 = (int)y0f, ix0 = (int)x0f;
        int iy1 = iy0 + 1,  ix1 = ix0 + 1;
        bool vy0 = (unsigned)iy0 < (unsigned)HH;
        bool vy1 = (unsigned)iy1 < (unsigned)HH;
        bool vx0 = (unsigned)ix0 < (unsigned)WW;
        bool vx1 = (unsigned)ix1 < (unsigned)WW;

        float w00 = (1.f - fy) * (1.f - fx) * m; if (!(vy0 && vx0)) w00 = 0.f;
        float w01 = (1.f - fy) * fx         * m; if (!(vy0 && vx1)) w01 = 0.f;
        float w10 = fy         * (1.f - fx) * m; if (!(vy1 && vx0)) w10 = 0.f;
        float w11 = fy         * fx         * m; if (!(vy1 && vx1)) w11 = 0.f;

        int cy0 = min(max(iy0, 0), HH - 1), cy1 = min(max(iy1, 0), HH - 1);
        int cx0 = min(max(ix0, 0), WW - 1), cx1 = min(max(ix1, 0), WW - 1);

        s_wgt4[k][p] = make_float4(w00, w01, w10, w11);
        s_off4[k][p] = make_int4((cy0 * WW + cx0) * 512, (cy0 * WW + cx1) * 512,
                                 (cy1 * WW + cx0) * 512, (cy1 * WW + cx1) * 512);
    }
    __syncthreads();

    // ================= Phase C: main deform GEMM (pipelined) =================
    int ow = wv * 32;                   // o base: wave owns 32 outputs
    f32x4 acc[2][4];
#pragma unroll
    for (int i = 0; i < 2; ++i)
#pragma unroll
        for (int j = 0; j < 4; ++j) acc[i][j] = (f32x4){0.f, 0.f, 0.f, 0.f};

    uint2 G[3][4];                      // 24 VGPR gather prefetch
    // prologue: gather+combine sub-chunk 0, issue sub-chunk-1 loads
    {
#pragma unroll
        for (int j = 0; j < 3; ++j) {
            int4 ob = s_off4[j][gp];
            G[j][0] = *(const uint2*)(xTb + ob.x + cg * 8);
            G[j][1] = *(const uint2*)(xTb + ob.y + cg * 8);
            G[j][2] = *(const uint2*)(xTb + ob.z + cg * 8);
            G[j][3] = *(const uint2*)(xTb + ob.w + cg * 8);
        }
#pragma unroll
        for (int j = 0; j < 3; ++j) {
            float4 gw = s_wgt4[j][gp];
            f32x2 v01 = gw.x * up2(G[j][0].x) + gw.y * up2(G[j][1].x)
                      + gw.z * up2(G[j][2].x) + gw.w * up2(G[j][3].x);
            f32x2 v23 = gw.x * up2(G[j][0].y) + gw.y * up2(G[j][1].y)
                      + gw.z * up2(G[j][2].y) + gw.w * up2(G[j][3].y);
            uint2 pk;
            pk.x = cvtpk(v01[0], v01[1]);
            pk.y = cvtpk(v23[0], v23[1]);
            *(uint2*)&s_samp[0][gp][j * 32 + cg * 4] = pk;
        }
#pragma unroll
        for (int j = 0; j < 3; ++j) {
            int4 ob = s_off4[3 + j][gp];
            G[j][0] = *(const uint2*)(xTb + ob.x + cg * 8);
            G[j][1] = *(const uint2*)(xTb + ob.y + cg * 8);
            G[j][2] = *(const uint2*)(xTb + ob.z + cg * 8);
            G[j][3] = *(const uint2*)(xTb + ob.w + cg * 8);
        }
        PIPE_BARRIER();
    }

    short8 a0c = *(const short8*)(wp + (ow +  0 + lm) * 32 + lq * 8);
    short8 a1c = *(const short8*)(wp + (ow + 16 + lm) * 32 + lq * 8);
    for (int sc = 0; sc < NSUB; ++sc) {
        bool doC = (sc + 1 < NSUB);
        bool doL = (sc + 2 < NSUB);
        int t1 = ((sc + 1) % 3) * 3;
        int t2 = ((sc + 2) % 3) * 3;
        int c2 = ((sc + 2) / 3) * (CCH * 2) + cg * 8;
        unsigned short (*__restrict__ bc)[SUBROW] = s_samp[sc & 1];
        unsigned short (*__restrict__ bn)[SUBROW] = s_samp[(sc + 1) & 1];
#pragma unroll
        for (int sl = 0; sl < 3; ++sl) {
            short8 b0 = *(const short8*)&bc[ 0 + lm][sl * 32 + lq * 8];
            short8 b1 = *(const short8*)&bc[16 + lm][sl * 32 + lq * 8];
            short8 b2 = *(const short8*)&bc[32 + lm][sl * 32 + lq * 8];
            short8 b3 = *(const short8*)&bc[48 + lm][sl * 32 + lq * 8];
            int r = sc * 3 + sl + 1;
            short8 a0n = a0c, a1n = a1c;
            if (r < NSTEP) {
                const unsigned short* wrn = wp + (size_t)r * COUT * 32;
                a0n = *(const short8*)(wrn + (ow +  0 + lm) * 32 + lq * 8);
                a1n = *(const short8*)(wrn + (ow + 16 + lm) * 32 + lq * 8);
            }
            if (doC) {                  // combine sub-chunk sc+1, tap sl -> bn
                float4 gw = s_wgt4[t1 + sl][gp];
                f32x2 v01 = gw.x * up2(G[sl][0].x) + gw.y * up2(G[sl][1].x)
                          + gw.z * up2(G[sl][2].x) + gw.w * up2(G[sl][3].x);
                f32x2 v23 = gw.x * up2(G[sl][0].y) + gw.y * up2(G[sl][1].y)
                          + gw.z * up2(G[sl][2].y) + gw.w * up2(G[sl][3].y);
                uint2 pk;
                pk.x = cvtpk(v01[0], v01[1]);
                pk.y = cvtpk(v23[0], v23[1]);
                *(uint2*)&bn[gp][sl * 32 + cg * 4] = pk;
            }
            if (doL) {                  // prefetch sub-chunk sc+2, tap sl
                int4 ob = s_off4[t2 + sl][gp];
                G[sl][0] = *(const uint2*)(xTb + ob.x + c2);
                G[sl][1] = *(const uint2*)(xTb + ob.y + c2);
                G[sl][2] = *(const uint2*)(xTb + ob.z + c2);
                G[sl][3] = *(const uint2*)(xTb + ob.w + c2);
            }
            acc[0][0] = __builtin_amdgcn_mfma_f32_16x16x32_bf16(a0c, b0, acc[0][0], 0, 0, 0);
            acc[0][1] = __builtin_amdgcn_mfma_f32_16x16x32_bf16(a0c, b1, acc[0][1], 0, 0, 0);
            acc[0][2] = __builtin_amdgcn_mfma_f32_16x16x32_bf16(a0c, b2, acc[0][2], 0, 0, 0);
            acc[0][3] = __builtin_amdgcn_mfma_f32_16x16x32_bf16(a0c, b3, acc[0][3], 0, 0, 0);
            acc[1][0] = __builtin_amdgcn_mfma_f32_16x16x32_bf16(a1c, b0, acc[1][0], 0, 0, 0);
            acc[1][1] = __builtin_amdgcn_mfma_f32_16x16x32_bf16(a1c, b1, acc[1][1], 0, 0, 0);
            acc[1][2] = __builtin_amdgcn_mfma_f32_16x16x32_bf16(a1c, b2, acc[1][2], 0, 0, 0);
            acc[1][3] = __builtin_amdgcn_mfma_f32_16x16x32_bf16(a1c, b3, acc[1][3], 0, 0, 0);
            a0c = a0n; a1c = a1n;
        }
        PIPE_BARRIER();
    }

    // ================= epilogue =================
    float* op = out + ((size_t)b * COUT) * PLANE + h * WW;
#pragma unroll
    for (int i = 0; i < 2; ++i) {
        int o0 = ow + i * 16 + lq * 4;
        f32x4 bv = *(const f32x4*)(bias + o0);
#pragma unroll
        for (int rg = 0; rg < 4; ++rg) {
#pragma unroll
            for (int j = 0; j < 4; ++j)
                op[(size_t)(o0 + rg) * PLANE + j * 16 + lm] = acc[i][j][rg] + bv[rg];
        }
    }
}

// ---------------------------------------------------------------------------
extern "C" void kernel_launch(void* const* d_in, const int* in_sizes, int n_in,
                              void* d_out, int out_size, void* d_ws, size_t ws_size,
                              hipStream_t stream) {
    const float* x    = (const float*)d_in[0];
    const float* wgt  = (const float*)d_in[1];
    const float* bias = (const float*)d_in[2];
    const float* pgw  = (const float*)d_in[3];
    const float* pgb  = (const float*)d_in[4];
    float* out = (float*)d_out;

    const size_t WPK_B = (size_t)NSTEP * COUT * 32 * 2;   //  1,179,648
    const size_t WPG_B = (size_t)NSTEP * 32 * 32 * 2;     //    147,456
    const size_t XT_B  = (size_t)BQ * PLANE * CIN * 2;    // 16,777,216
    unsigned short* wpk = (unsigned short*)d_ws;
    unsigned short* wpg = (unsigned short*)((char*)d_ws + WPK_B);
    unsigned short* xT  = (unsigned short*)((char*)d_ws + WPK_B + WPG_B);
    float*          pv  = (float*)((char*)d_ws + WPK_B + WPG_B + XT_B);  // 3.54 MB

    k_prep  <<<NPREP, 256, 0, stream>>>(x, xT, wgt, wpk, pgw, wpg);
    k_params<<<BQ * HH / 2, 512, 0, stream>>>(xT, wpg, pgb, pv);
    k_fused <<<BQ * HH, 512, 0, stream>>>(xT, wpk, pv, bias, out);
}